// Round 7
// baseline (53722.107 us; speedup 1.0000x reference)
//
#include <hip/hip_runtime.h>

#define T_STEPS 8192
#define HID 1024
#define G4 4096
#define NBLK 128    // blocks per layer; grid = 256
#define NTHR 512    // 8 waves
#define NSLOT 8     // global rotation depth

typedef unsigned int uint32;

// Global comm (memset 0xFF each launch): tagged fp32 h values.
// Slot s = t & 7; tag = (t>>3) & 15 in the 4 low mantissa bits.
struct Comm {
    uint32 hA[NSLOT][HID];   // layer-0 h
    uint32 hB[NSLOT][HID];   // layer-1 h
};

__device__ inline float sigm(float x) { return 1.0f / (1.0f + __expf(-x)); }
__device__ inline float tanh_f(float x) {
    x = fminf(fmaxf(x, -15.f), 15.f);
    float e = __expf(-2.0f * x);
    return (1.0f - e) / (1.0f + e);
}
__device__ inline uint32 tagf(float f, uint32 tg) {
    union { float f; uint32 u; } a; a.f = f;
    return (a.u & ~15u) | tg;
}

// out[m][perm(n)] = A[m][:] . W[n][:] + bi[n] + bh[n]
// perm: j = n&1023, gate = n>>10; idx = (j>>3)*32 + (j&7)*4 + gate
__global__ __launch_bounds__(256)
void gemm_xg(const float* __restrict__ A, const float* __restrict__ W,
             const float* __restrict__ bi, const float* __restrict__ bh,
             float* __restrict__ out)
{
    __shared__ float As[16][65];
    __shared__ float Bs[16][65];
    const int tid = threadIdx.x;
    const int m0 = blockIdx.y * 64, n0 = blockIdx.x * 64;
    const int tm = tid & 15, tn = tid >> 4;
    const int row = tid >> 2, q = tid & 3;
    float acc[4][4] = {{0.f}};
    for (int k0 = 0; k0 < HID; k0 += 16) {
        float4 a = *(const float4*)(A + (size_t)(m0 + row) * HID + k0 + q * 4);
        float4 b = *(const float4*)(W + (size_t)(n0 + row) * HID + k0 + q * 4);
        __syncthreads();
        As[q*4+0][row] = a.x; As[q*4+1][row] = a.y; As[q*4+2][row] = a.z; As[q*4+3][row] = a.w;
        Bs[q*4+0][row] = b.x; Bs[q*4+1][row] = b.y; Bs[q*4+2][row] = b.z; Bs[q*4+3][row] = b.w;
        __syncthreads();
#pragma unroll
        for (int kk = 0; kk < 16; ++kk) {
            float av[4], bv[4];
#pragma unroll
            for (int i = 0; i < 4; ++i) { av[i] = As[kk][tm*4+i]; bv[i] = Bs[kk][tn*4+i]; }
#pragma unroll
            for (int i = 0; i < 4; ++i)
#pragma unroll
                for (int j = 0; j < 4; ++j) acc[i][j] += av[i] * bv[j];
        }
    }
#pragma unroll
    for (int i = 0; i < 4; ++i) {
        int m = m0 + tm * 4 + i;
#pragma unroll
        for (int j = 0; j < 4; ++j) {
            int n = n0 + tn * 4 + j;
            float v = acc[i][j] + bi[n] + bh[n];
            int jd = n & (HID - 1), gate = n >> 10;
            out[(size_t)m * G4 + (jd >> 3) * 32 + (jd & 7) * 4 + gate] = v;
        }
    }
}

#define LD_WG  __HIP_MEMORY_SCOPE_WORKGROUP
#define LD_AG  __HIP_MEMORY_SCOPE_AGENT

// Incremental poll: forward each 64-word segment to LDS + flag it the moment
// its tags validate; only pending segments are re-loaded.
__device__ inline void poll_stream(const uint32* __restrict__ buf, uint32 tg,
                                   int lane, float* __restrict__ lds,
                                   int* __restrict__ flags, int fval)
{
    uint32 v[16];
    unsigned pending = 0xFFFFu;
    while (pending) {
#pragma unroll
        for (int r = 0; r < 16; ++r)
            if (pending & (1u << r))
                v[r] = __hip_atomic_load(&buf[r * 64 + lane], __ATOMIC_RELAXED, LD_AG);
        unsigned np = pending;
#pragma unroll
        for (int r = 0; r < 16; ++r) {
            if (!(pending & (1u << r))) continue;
            if (__all((v[r] & 15u) == tg)) {
                union { uint32 u; float f; } c; c.u = v[r];
                lds[r * 64 + lane] = c.f;
                if (lane == 0)
                    __hip_atomic_store(&flags[r], fval, __ATOMIC_RELEASE, LD_WG);
                np &= ~(1u << r);
            }
        }
        pending = np;
    }
}

// Fused 2-layer persistent LSTM, segment-streamed, barrier-free steady state.
// Blocks 0..127 = layer 0; 128..255 = layer 1 (W_ih1 slice in 64 VGPRs/thread).
// LDS W layout gate-interleaved: Wl[wave][col][gate] -> one ds_read_b128
// yields all 4 gate weights for (wave, col).
__global__ __launch_bounds__(NTHR)
void lstm_fused(const float* __restrict__ Whh0, const float* __restrict__ xg,
                const float* __restrict__ Wih1, const float* __restrict__ Whh1,
                const float* __restrict__ bih1, const float* __restrict__ bhh1,
                float* __restrict__ outF, Comm* __restrict__ cm)
{
    __shared__ float Wl[8 * HID * 4];   // 131 KB
    __shared__ float hlA[2][HID];
    __shared__ float hlB[2][HID];
    __shared__ int flagA[2][16];
    __shared__ int flagB[2][16];
    __shared__ int prog[8];
    __shared__ int bpOK;
    const int blk = blockIdx.x, tid = threadIdx.x;
    const int wave = tid >> 6, lane = tid & 63;
    const int kb = (blk < NBLK) ? blk : blk - NBLK;

    if (tid < 16) { flagA[0][tid] = -2; flagA[1][tid] = -1;
                    flagB[0][tid] = -2; flagB[1][tid] = -1; }
    if (tid < 8) prog[tid] = -1;
    if (tid == 0) bpOK = -1;
    for (int i = tid; i < HID; i += NTHR) {
        hlA[0][i] = 0.f; hlA[1][i] = 0.f; hlB[0][i] = 0.f; hlB[1][i] = 0.f;
    }
    // stage W_hh slice gate-interleaved: Wl[(w*HID + c)*4 + g]
    {
        const float* Wsrc = (blk < NBLK) ? Whh0 : Whh1;
#pragma unroll
        for (int i = 0; i < 16; ++i) {
            int l = i * NTHR + tid;          // float4 index 0..8191
            int r = l >> 8, c4 = l & 255;
            int w = r >> 2, g = r & 3;
            float4 v = ((const float4*)(Wsrc + (size_t)(g * HID + 8 * kb + w) * HID))[c4];
            float* dst = Wl + ((size_t)w * HID + c4 * 4) * 4 + g;
            dst[0] = v.x; dst[4] = v.y; dst[8] = v.z; dst[12] = v.w;
        }
    }

    if (blk < NBLK) {
        // ---------------- layer 0 ----------------
        const int k = kb;
        float c_state = 0.f;
        float nx0 = 0.f, nx1 = 0.f, nx2 = 0.f, nx3 = 0.f;
        if (lane == 0) {
            const float* xp = xg + k * 32 + wave * 4;
            nx0 = xp[0]; nx1 = xp[1]; nx2 = xp[2]; nx3 = xp[3];
        }
        __syncthreads();

        for (int t = 0; t < T_STEPS; ++t) {
            const int pm = (t - 1) & 1;      // parity holding h0_{t-1}
            float x0 = nx0, x1 = nx1, x2 = nx2, x3 = nx3;
            if (lane == 0 && t + 1 < T_STEPS) {
                const float* xp = xg + (size_t)(t + 1) * G4 + k * 32 + wave * 4;
                nx0 = xp[0]; nx1 = xp[1]; nx2 = xp[2]; nx3 = xp[3];
            }
            float a0 = 0.f, a1 = 0.f, a2 = 0.f, a3 = 0.f;
            const float* wb = Wl + (size_t)wave * HID * 4;
#pragma unroll
            for (int u = 0; u < 16; ++u) {
                while (__hip_atomic_load(&flagA[pm][u], __ATOMIC_ACQUIRE, LD_WG) != t - 1) {}
                float hv = hlA[pm][u * 64 + lane];
                float4 wv = *(const float4*)(wb + (u * 64 + lane) * 4);
                a0 += wv.x * hv; a1 += wv.y * hv; a2 += wv.z * hv; a3 += wv.w * hv;
            }
#pragma unroll
            for (int off = 32; off > 0; off >>= 1) {
                a0 += __shfl_xor(a0, off, 64);
                a1 += __shfl_xor(a1, off, 64);
                a2 += __shfl_xor(a2, off, 64);
                a3 += __shfl_xor(a3, off, 64);
            }
            // backpressure: publish h0_t overwrites h0_{t-8}; need layer-1 done
            // with it, proven by hB[t-7] complete -> spin bpOK >= t-7.
            while (__hip_atomic_load(&bpOK, __ATOMIC_RELAXED, LD_WG) < t - 7) {}
            if (lane == 0) {
                float ig = sigm(x0 + a0);
                float fg = sigm(x1 + a1);
                float gg = tanh_f(x2 + a2);
                float og = sigm(x3 + a3);
                c_state = fg * c_state + ig * gg;
                float h = og * tanh_f(c_state);
                __hip_atomic_store(&cm->hA[t & 7][8 * k + wave],
                                   tagf(h, (t >> 3) & 15), __ATOMIC_RELAXED, LD_AG);
            }
            if (t == T_STEPS - 1) break;

            if (wave == 0) {
                // backward guard: rewriting hlA[t&1], last read during iter t-1
                if (lane < 8)
                    while (__hip_atomic_load(&prog[lane], __ATOMIC_ACQUIRE, LD_WG) < t - 1) {}
                poll_stream(cm->hA[t & 7], (t >> 3) & 15, lane, hlA[t & 1], flagA[t & 1], t);
                if (lane == 0) __hip_atomic_store(&prog[0], t, __ATOMIC_RELEASE, LD_WG);
            } else if (wave == 1) {
                // verify hB[t-6] complete -> bpOK = t-6
                if (t >= 6) {
                    const int s = t - 6;
                    const uint32 tg = (s >> 3) & 15;
                    const uint32* hb = cm->hB[s & 7];
                    uint32 v[16];
                    for (;;) {
                        bool ok = true;
#pragma unroll
                        for (int r = 0; r < 16; ++r)
                            v[r] = __hip_atomic_load(&hb[r * 64 + lane], __ATOMIC_RELAXED, LD_AG);
#pragma unroll
                        for (int r = 0; r < 16; ++r) ok &= ((v[r] & 15u) == tg);
                        if (__all(ok)) break;
                    }
                    if (lane == 0) __hip_atomic_store(&bpOK, s, __ATOMIC_RELEASE, LD_WG);
                }
                if (lane == 0) __hip_atomic_store(&prog[1], t, __ATOMIC_RELEASE, LD_WG);
            } else {
                if (lane == 0) __hip_atomic_store(&prog[wave], t, __ATOMIC_RELEASE, LD_WG);
            }
        }
    } else {
        // ---------------- layer 1 ----------------
        const int j = 8 * kb + wave;
        float wreg[4][16];
#pragma unroll
        for (int g = 0; g < 4; ++g)
#pragma unroll
            for (int u = 0; u < 16; ++u)
                wreg[g][u] = Wih1[(size_t)(g * HID + j) * HID + u * 64 + lane];
        float bia[4];
#pragma unroll
        for (int g = 0; g < 4; ++g)
            bia[g] = bih1[g * HID + j] + bhh1[g * HID + j];
        float c_state = 0.f;
        __syncthreads();

        for (int t = 0; t < T_STEPS; ++t) {
            const int pA = t & 1, pB = (t - 1) & 1;
            if (wave == 0) {
                // h0_t -> hlA[pA]; guard: hlA[pA] last read during iter t-2
                if (t >= 2 && lane < 8)
                    while (__hip_atomic_load(&prog[lane], __ATOMIC_ACQUIRE, LD_WG) < t - 2) {}
                poll_stream(cm->hA[t & 7], (t >> 3) & 15, lane, hlA[pA], flagA[pA], t);
            } else if (wave == 1 && t >= 1) {
                // h1_{t-1} -> hlB[pB]; guard: hlB[pB] last read during iter t-2
                if (t >= 3 && lane < 8)
                    while (__hip_atomic_load(&prog[lane], __ATOMIC_ACQUIRE, LD_WG) < t - 2) {}
                poll_stream(cm->hB[(t - 1) & 7], ((t - 1) >> 3) & 15, lane,
                            hlB[pB], flagB[pB], t - 1);
            }
            float a0 = 0.f, a1 = 0.f, a2 = 0.f, a3 = 0.f;
            const float* wb = Wl + (size_t)wave * HID * 4;
#pragma unroll
            for (int u = 0; u < 16; ++u) {   // recurrent part first (arrives first)
                while (__hip_atomic_load(&flagB[pB][u], __ATOMIC_ACQUIRE, LD_WG) != t - 1) {}
                float hv = hlB[pB][u * 64 + lane];
                float4 wv = *(const float4*)(wb + (u * 64 + lane) * 4);
                a0 += wv.x * hv; a1 += wv.y * hv; a2 += wv.z * hv; a3 += wv.w * hv;
            }
#pragma unroll
            for (int u = 0; u < 16; ++u) {   // input part (h0_t streaming in)
                while (__hip_atomic_load(&flagA[pA][u], __ATOMIC_ACQUIRE, LD_WG) != t) {}
                float hv = hlA[pA][u * 64 + lane];
                a0 += wreg[0][u] * hv; a1 += wreg[1][u] * hv;
                a2 += wreg[2][u] * hv; a3 += wreg[3][u] * hv;
            }
#pragma unroll
            for (int off = 32; off > 0; off >>= 1) {
                a0 += __shfl_xor(a0, off, 64);
                a1 += __shfl_xor(a1, off, 64);
                a2 += __shfl_xor(a2, off, 64);
                a3 += __shfl_xor(a3, off, 64);
            }
            if (lane == 0) {
                float ig = sigm(bia[0] + a0);
                float fg = sigm(bia[1] + a1);
                float gg = tanh_f(bia[2] + a2);
                float og = sigm(bia[3] + a3);
                c_state = fg * c_state + ig * gg;
                float h = og * tanh_f(c_state);
                if (t == T_STEPS - 1)
                    outF[j] = h;
                else
                    __hip_atomic_store(&cm->hB[t & 7][j],
                                       tagf(h, (t >> 3) & 15), __ATOMIC_RELAXED, LD_AG);
            }
            if (t == T_STEPS - 1) break;
            if (lane == 0)
                __hip_atomic_store(&prog[wave], t, __ATOMIC_RELEASE, LD_WG);
        }
    }
}

extern "C" void kernel_launch(void* const* d_in, const int* in_sizes, int n_in,
                              void* d_out, int out_size, void* d_ws, size_t ws_size,
                              hipStream_t stream)
{
    const float* x    = (const float*)d_in[0];
    const float* Wih0 = (const float*)d_in[1];
    const float* Whh0 = (const float*)d_in[2];
    const float* bih0 = (const float*)d_in[3];
    const float* bhh0 = (const float*)d_in[4];
    const float* Wih1 = (const float*)d_in[5];
    const float* Whh1 = (const float*)d_in[6];
    const float* bih1 = (const float*)d_in[7];
    const float* bhh1 = (const float*)d_in[8];

    char* ws = (char*)d_ws;
    float* xg = (float*)ws;                     // 134217728 B
    Comm*  cm = (Comm*)(ws + 134217728);        // 65536 B

    (void)hipMemsetAsync(ws + 134217728, 0xFF, sizeof(Comm), stream);

    dim3 gg(G4 / 64, T_STEPS / 64);
    gemm_xg<<<gg, 256, 0, stream>>>(x, Wih0, bih0, bhh0, xg);
    lstm_fused<<<2 * NBLK, NTHR, 0, stream>>>(Whh0, xg, Wih1, Whh1, bih1, bhh1,
                                              (float*)d_out, cm);
}

// Round 8
// 36229.837 us; speedup vs baseline: 1.4828x; 1.4828x over previous
//
#include <hip/hip_runtime.h>

#define T_STEPS 8192
#define HID 1024
#define G4 4096
#define NBLK 128    // blocks per layer; grid = 256
#define NTHR 512    // 8 waves
#define NSLOT 8     // rotation depth

typedef unsigned int uint32;

// Global comm (memset 0xFF each launch): tagged fp32 h values.
// Slot s = t & 7; tag = (t>>3) & 15 in the 4 low mantissa bits.
// Overwrite safety at depth 8: publishing h_t requires gathering h_{t-1},
// which (transitively, all-to-all each step) bounds any block's lag at <2
// steps within a cohort; cross-cohort guarded by wave2's hB scan (see loop).
struct Comm {
    uint32 hA[NSLOT][HID];   // layer-0 h
    uint32 hB[NSLOT][HID];   // layer-1 h
};

#define LD_AG  __HIP_MEMORY_SCOPE_AGENT

__device__ inline float sigm(float x) { return 1.0f / (1.0f + __expf(-x)); }
__device__ inline float tanh_f(float x) {
    x = fminf(fmaxf(x, -15.f), 15.f);
    float e = __expf(-2.0f * x);
    return (1.0f - e) / (1.0f + e);
}
__device__ inline uint32 tagf(float f, uint32 tg) {
    union { float f; uint32 u; } a; a.f = f;
    return (a.u & ~15u) | tg;
}

// out[m][perm(n)] = A[m][:] . W[n][:] + bi[n] + bh[n]
// perm: j = n&1023, gate = n>>10; idx = (j>>3)*32 + (j&7)*4 + gate
__global__ __launch_bounds__(256)
void gemm_xg(const float* __restrict__ A, const float* __restrict__ W,
             const float* __restrict__ bi, const float* __restrict__ bh,
             float* __restrict__ out)
{
    __shared__ float As[16][65];
    __shared__ float Bs[16][65];
    const int tid = threadIdx.x;
    const int m0 = blockIdx.y * 64, n0 = blockIdx.x * 64;
    const int tm = tid & 15, tn = tid >> 4;
    const int row = tid >> 2, q = tid & 3;
    float acc[4][4] = {{0.f}};
    for (int k0 = 0; k0 < HID; k0 += 16) {
        float4 a = *(const float4*)(A + (size_t)(m0 + row) * HID + k0 + q * 4);
        float4 b = *(const float4*)(W + (size_t)(n0 + row) * HID + k0 + q * 4);
        __syncthreads();
        As[q*4+0][row] = a.x; As[q*4+1][row] = a.y; As[q*4+2][row] = a.z; As[q*4+3][row] = a.w;
        Bs[q*4+0][row] = b.x; Bs[q*4+1][row] = b.y; Bs[q*4+2][row] = b.z; Bs[q*4+3][row] = b.w;
        __syncthreads();
#pragma unroll
        for (int kk = 0; kk < 16; ++kk) {
            float av[4], bv[4];
#pragma unroll
            for (int i = 0; i < 4; ++i) { av[i] = As[kk][tm*4+i]; bv[i] = Bs[kk][tn*4+i]; }
#pragma unroll
            for (int i = 0; i < 4; ++i)
#pragma unroll
                for (int j = 0; j < 4; ++j) acc[i][j] += av[i] * bv[j];
        }
    }
#pragma unroll
    for (int i = 0; i < 4; ++i) {
        int m = m0 + tm * 4 + i;
#pragma unroll
        for (int j = 0; j < 4; ++j) {
            int n = n0 + tn * 4 + j;
            float v = acc[i][j] + bi[n] + bh[n];
            int jd = n & (HID - 1), gate = n >> 10;
            out[(size_t)m * G4 + (jd >> 3) * 32 + (jd & 7) * 4 + gate] = v;
        }
    }
}

// Poll-and-gather 8 segments (one half of h): repeat 8 tagged loads/lane until
// all tags match, then forward to LDS. Two waves cover the full vector.
__device__ inline void poll8(const uint32* __restrict__ buf, uint32 tg,
                             int lane, float* __restrict__ lds)
{
    uint32 v[8];
    for (;;) {
#pragma unroll
        for (int r = 0; r < 8; ++r)
            v[r] = __hip_atomic_load(&buf[r * 64 + lane], __ATOMIC_RELAXED, LD_AG);
        bool ok = true;
#pragma unroll
        for (int r = 0; r < 8; ++r) ok &= ((v[r] & 15u) == tg);
        if (__all(ok)) break;
    }
#pragma unroll
    for (int r = 0; r < 8; ++r) {
        union { uint32 u; float f; } c; c.u = v[r];
        lds[r * 64 + lane] = c.f;
    }
}

// Full-vector tag scan (no LDS forward) — used for backpressure verification.
__device__ inline void scan16(const uint32* __restrict__ buf, uint32 tg, int lane)
{
    uint32 v[16];
    for (;;) {
        bool ok = true;
#pragma unroll
        for (int r = 0; r < 16; ++r)
            v[r] = __hip_atomic_load(&buf[r * 64 + lane], __ATOMIC_RELAXED, LD_AG);
#pragma unroll
        for (int r = 0; r < 16; ++r) ok &= ((v[r] & 15u) == tg);
        if (__all(ok)) break;
    }
}

// Fused 2-layer persistent LSTM. 256 blocks x 512 thr, 1 block/CU.
// Blocks 0..127 = layer 0 (xg precomputed); blocks 128..255 = layer 1
// (W_ih1 slice in 64 VGPRs/thread, W_hh1 slice in LDS).
__global__ __launch_bounds__(NTHR)
void lstm_fused(const float* __restrict__ Whh0, const float* __restrict__ xg,
                const float* __restrict__ Wih1, const float* __restrict__ Whh1,
                const float* __restrict__ bih1, const float* __restrict__ bhh1,
                float* __restrict__ outF, Comm* __restrict__ cm)
{
    __shared__ float Wl[32 * HID];   // 131 KB, rows [w*4+gate][1024]
    __shared__ float hlA[HID];
    __shared__ float hlB[HID];
    const int blk = blockIdx.x, tid = threadIdx.x;
    const int wave = tid >> 6, lane = tid & 63;
    const int kb = (blk < NBLK) ? blk : blk - NBLK;

    // stage W_hh slice: LDS row r=w*4+g <- global row g*1024 + (8kb+w)
    {
        const float* Wsrc = (blk < NBLK) ? Whh0 : Whh1;
#pragma unroll
        for (int i = 0; i < 16; ++i) {
            int l = i * NTHR + tid;
            int r = l >> 8, c = l & 255;
            int w = r >> 2, g = r & 3;
            ((float4*)(Wl + r * HID))[c] =
                ((const float4*)(Wsrc + (size_t)(g * HID + 8 * kb + w) * HID))[c];
        }
    }
    for (int i = tid; i < HID; i += NTHR) { hlA[i] = 0.f; hlB[i] = 0.f; }

    if (blk < NBLK) {
        // ---------------- layer 0 ----------------
        const int k = kb;
        float c_state = 0.f;
        float nx0 = 0.f, nx1 = 0.f, nx2 = 0.f, nx3 = 0.f;
        if (lane == 0) {
            const float* xp = xg + k * 32 + wave * 4;
            nx0 = xp[0]; nx1 = xp[1]; nx2 = xp[2]; nx3 = xp[3];
        }
        __syncthreads();

        for (int t = 0; t < T_STEPS; ++t) {
            float x0 = nx0, x1 = nx1, x2 = nx2, x3 = nx3;
            if (lane == 0 && t + 1 < T_STEPS) {
                const float* xp = xg + (size_t)(t + 1) * G4 + k * 32 + wave * 4;
                nx0 = xp[0]; nx1 = xp[1]; nx2 = xp[2]; nx3 = xp[3];
            }
            float a0 = 0.f, a1 = 0.f, a2 = 0.f, a3 = 0.f;
            const float* wb = Wl + wave * 4 * HID;
#pragma unroll 4
            for (int u = 0; u < 16; ++u) {
                float hv = hlA[u * 64 + lane];
                a0 += wb[0 * HID + u * 64 + lane] * hv;
                a1 += wb[1 * HID + u * 64 + lane] * hv;
                a2 += wb[2 * HID + u * 64 + lane] * hv;
                a3 += wb[3 * HID + u * 64 + lane] * hv;
            }
#pragma unroll
            for (int off = 32; off > 0; off >>= 1) {
                a0 += __shfl_xor(a0, off, 64);
                a1 += __shfl_xor(a1, off, 64);
                a2 += __shfl_xor(a2, off, 64);
                a3 += __shfl_xor(a3, off, 64);
            }
            if (lane == 0) {
                float ig = sigm(x0 + a0);
                float fg = sigm(x1 + a1);
                float gg = tanh_f(x2 + a2);
                float og = sigm(x3 + a3);
                c_state = fg * c_state + ig * gg;
                float h = og * tanh_f(c_state);
                // publish h0_t (overwrites h0_{t-8}; guarded by step t-1's
                // wave2 scan of hB[t-5] => layer-1 gathered h0_{t-5} fully)
                __hip_atomic_store(&cm->hA[t & 7][8 * k + wave],
                                   tagf(h, (t >> 3) & 15), __ATOMIC_RELAXED, LD_AG);
            }
            if (t == T_STEPS - 1) break;
            __syncthreads();   // everyone done reading hlA
            if (wave == 0) {
                poll8(cm->hA[t & 7], (t >> 3) & 15, lane, hlA);            // segs 0-7
            } else if (wave == 1) {
                poll8(cm->hA[t & 7] + 512, (t >> 3) & 15, lane, hlA + 512); // segs 8-15
            } else if (wave == 2 && t >= 4) {
                scan16(cm->hB[(t - 4) & 7], ((t - 4) >> 3) & 15, lane);    // backpressure
            }
            __syncthreads();   // hlA = h0_t
        }
    } else {
        // ---------------- layer 1 ----------------
        const int j = 8 * kb + wave;
        float wreg[4][16];
#pragma unroll
        for (int g = 0; g < 4; ++g)
#pragma unroll
            for (int u = 0; u < 16; ++u)
                wreg[g][u] = Wih1[(size_t)(g * HID + j) * HID + u * 64 + lane];
        float bia[4];
#pragma unroll
        for (int g = 0; g < 4; ++g)
            bia[g] = bih1[g * HID + j] + bhh1[g * HID + j];
        float c_state = 0.f;
        __syncthreads();

        for (int t = 0; t < T_STEPS; ++t) {
            if (wave == 0) {
                poll8(cm->hA[t & 7], (t >> 3) & 15, lane, hlA);             // h0_t lo
            } else if (wave == 1) {
                poll8(cm->hA[t & 7] + 512, (t >> 3) & 15, lane, hlA + 512); // h0_t hi
            } else if (wave == 2 && t >= 1) {
                poll8(cm->hB[(t - 1) & 7], ((t - 1) >> 3) & 15, lane, hlB); // h1_{t-1} lo
            } else if (wave == 3 && t >= 1) {
                poll8(cm->hB[(t - 1) & 7] + 512, ((t - 1) >> 3) & 15, lane, hlB + 512);
            }
            __syncthreads();   // hlA = h0_t, hlB = h1_{t-1}
            float a0 = 0.f, a1 = 0.f, a2 = 0.f, a3 = 0.f;
            const float* wb = Wl + wave * 4 * HID;
#pragma unroll
            for (int u = 0; u < 16; ++u) {
                float h0v = hlA[u * 64 + lane];
                float h1v = hlB[u * 64 + lane];
                a0 += wb[0 * HID + u * 64 + lane] * h1v + wreg[0][u] * h0v;
                a1 += wb[1 * HID + u * 64 + lane] * h1v + wreg[1][u] * h0v;
                a2 += wb[2 * HID + u * 64 + lane] * h1v + wreg[2][u] * h0v;
                a3 += wb[3 * HID + u * 64 + lane] * h1v + wreg[3][u] * h0v;
            }
#pragma unroll
            for (int off = 32; off > 0; off >>= 1) {
                a0 += __shfl_xor(a0, off, 64);
                a1 += __shfl_xor(a1, off, 64);
                a2 += __shfl_xor(a2, off, 64);
                a3 += __shfl_xor(a3, off, 64);
            }
            if (lane == 0) {
                float ig = sigm(bia[0] + a0);
                float fg = sigm(bia[1] + a1);
                float gg = tanh_f(bia[2] + a2);
                float og = sigm(bia[3] + a3);
                c_state = fg * c_state + ig * gg;
                float h = og * tanh_f(c_state);
                if (t == T_STEPS - 1)
                    outF[j] = h;   // untagged, full precision
                else
                    __hip_atomic_store(&cm->hB[t & 7][j],
                                       tagf(h, (t >> 3) & 15), __ATOMIC_RELAXED, LD_AG);
            }
            if (t == T_STEPS - 1) break;
            __syncthreads();   // all done reading hlA/hlB before next poll
        }
    }
}

extern "C" void kernel_launch(void* const* d_in, const int* in_sizes, int n_in,
                              void* d_out, int out_size, void* d_ws, size_t ws_size,
                              hipStream_t stream)
{
    const float* x    = (const float*)d_in[0];
    const float* Wih0 = (const float*)d_in[1];
    const float* Whh0 = (const float*)d_in[2];
    const float* bih0 = (const float*)d_in[3];
    const float* bhh0 = (const float*)d_in[4];
    const float* Wih1 = (const float*)d_in[5];
    const float* Whh1 = (const float*)d_in[6];
    const float* bih1 = (const float*)d_in[7];
    const float* bhh1 = (const float*)d_in[8];

    char* ws = (char*)d_ws;
    float* xg = (float*)ws;                     // 134217728 B
    Comm*  cm = (Comm*)(ws + 134217728);        // 65536 B

    // 0xFF fill: tag = 15; slot s only expects tag 15 at t = s + 120, by which
    // point the slot has been rewritten 15 times — init pattern long gone.
    (void)hipMemsetAsync(ws + 134217728, 0xFF, sizeof(Comm), stream);

    dim3 gg(G4 / 64, T_STEPS / 64);
    gemm_xg<<<gg, 256, 0, stream>>>(x, Wih0, bih0, bhh0, xg);
    lstm_fused<<<2 * NBLK, NTHR, 0, stream>>>(Whh0, xg, Wih1, Whh1, bih1, bhh1,
                                              (float*)d_out, cm);
}